// Round 1
// 547.043 us; speedup vs baseline: 1.0065x; 1.0065x over previous
//
#include <hip/hip_runtime.h>
#include <hip/hip_bf16.h>
#include <cstdint>
#include <cstddef>

#define S_TOK 2048
#define M_DIM 768
#define H_DIM 3072
#define E_NUM 16
#define CAP   256   // 2*S/E

using s16x8 = __attribute__((ext_vector_type(8))) short;  // 8 bf16 (4 VGPRs)
using f32x4 = __attribute__((ext_vector_type(4))) float;

__device__ __forceinline__ unsigned short f2bf(float f) {
    unsigned u = __float_as_uint(f);
    unsigned r = 0x7fffu + ((u >> 16) & 1u);
    return (unsigned short)((u + r) >> 16);
}

__device__ __forceinline__ void async16(const void* g, void* l) {
    __builtin_amdgcn_global_load_lds((const __attribute__((address_space(1))) void*)g,
                                     (__attribute__((address_space(3))) void*)l, 16, 0, 0);
}

// ---------------------------------------------------------------------------
// Kernel 1: gating — logits = x@wg, softmax, top1/top2 (one wave per token)
// ---------------------------------------------------------------------------
__global__ void gating_kernel(const float* __restrict__ x, const float* __restrict__ wg,
                              int* __restrict__ e1o, int* __restrict__ e2o,
                              float* __restrict__ g1o, float* __restrict__ g2o, int ntok) {
    int gid  = blockIdx.x * blockDim.x + threadIdx.x;
    int tok  = gid >> 6;
    int lane = threadIdx.x & 63;
    if (tok >= ntok) return;
    const float* xr = x + (size_t)tok * M_DIM;
    float acc[E_NUM];
#pragma unroll
    for (int e = 0; e < E_NUM; ++e) acc[e] = 0.f;
    for (int m = lane; m < M_DIM; m += 64) {
        float xv = xr[m];
        const float* wr = wg + (size_t)m * E_NUM;
#pragma unroll
        for (int e = 0; e < E_NUM; ++e) acc[e] += xv * wr[e];
    }
#pragma unroll
    for (int off = 32; off >= 1; off >>= 1) {
#pragma unroll
        for (int e = 0; e < E_NUM; ++e) acc[e] += __shfl_xor(acc[e], off, 64);
    }
    if (lane == 0) {
        float mx = acc[0];
#pragma unroll
        for (int e = 1; e < E_NUM; ++e) mx = fmaxf(mx, acc[e]);
        float p[E_NUM]; float s = 0.f;
#pragma unroll
        for (int e = 0; e < E_NUM; ++e) { p[e] = expf(acc[e] - mx); s += p[e]; }
        float inv = 1.f / s;
        int b1 = 0; float v1 = -1.f;
#pragma unroll
        for (int e = 0; e < E_NUM; ++e) { if (p[e] > v1) { v1 = p[e]; b1 = e; } }
        int b2 = 0; float v2 = -1.f;
#pragma unroll
        for (int e = 0; e < E_NUM; ++e) { if (e != b1 && p[e] > v2) { v2 = p[e]; b2 = e; } }
        e1o[tok] = b1; e2o[tok] = b2;
        g1o[tok] = v1 * inv; g2o[tok] = v2 * inv;
    }
}

// ---------------------------------------------------------------------------
// Kernel 2: assignment — capacity positions via ballot prefix scan.
// ---------------------------------------------------------------------------
__global__ void assign_kernel(const int* __restrict__ e1a, const int* __restrict__ e2a,
                              const float* __restrict__ g1a, const float* __restrict__ g2a,
                              int* __restrict__ slot1, int* __restrict__ slot2,
                              float* __restrict__ w1, float* __restrict__ w2,
                              int* __restrict__ tfs, int G) {
    int g    = blockIdx.x;
    int tid  = threadIdx.x;
    int w    = tid >> 6;
    int lane = tid & 63;
    __shared__ int cnt1s[E_NUM];

    for (int i = tid; i < E_NUM * CAP; i += 1024) tfs[(size_t)g * E_NUM * CAP + i] = -1;
    __syncthreads();

    {
        int cnt = 0;
        for (int base = 0; base < S_TOK; base += 64) {
            int t = g * S_TOK + base + lane;
            bool pred = (e1a[t] == w);
            unsigned long long bal = __ballot(pred);
            int prefix = __popcll(bal & ((1ull << lane) - 1ull));
            if (pred) {
                int pos = cnt + prefix;
                if (pos < CAP) {
                    slot1[t] = w * CAP + pos;
                    tfs[((size_t)g * E_NUM + w) * CAP + pos] = base + lane;
                } else {
                    slot1[t] = -1;
                }
            }
            cnt += __popcll(bal);
        }
        if (lane == 0) cnt1s[w] = cnt < CAP ? cnt : CAP;
    }
    __syncthreads();
    {
        int cnt = cnt1s[w];
        for (int base = 0; base < S_TOK; base += 64) {
            int t = g * S_TOK + base + lane;
            bool pred = (e2a[t] == w);
            unsigned long long bal = __ballot(pred);
            int prefix = __popcll(bal & ((1ull << lane) - 1ull));
            if (pred) {
                int pos = cnt + prefix;
                if (pos < CAP) {
                    slot2[t] = w * CAP + pos;
                    tfs[((size_t)g * E_NUM + w) * CAP + pos] = base + lane;
                } else {
                    slot2[t] = -1;
                }
            }
            cnt += __popcll(bal);
        }
    }
    __syncthreads();
    for (int t = tid; t < S_TOK; t += 1024) {
        int gt = g * S_TOK + t;
        float a = slot1[gt] >= 0 ? g1a[gt] : 0.f;
        float b = slot2[gt] >= 0 ? g2a[gt] : 0.f;
        float denom = a + b;
        if (!(denom > 0.f)) denom = 1.f;
        w1[gt] = a / denom;
        w2[gt] = b / denom;
    }
}

// ---------------------------------------------------------------------------
// Kernel 3: x fp32 -> bf16, plus one zero row appended at row ntok
// ---------------------------------------------------------------------------
__global__ void convert_x_kernel(const float* __restrict__ x, unsigned short* __restrict__ xb,
                                 int ntok) {
    int i4 = blockIdx.x * blockDim.x + threadIdx.x;
    size_t base = (size_t)i4 * 4;
    size_t n_real = (size_t)ntok * M_DIM;
    size_t n_tot  = (size_t)(ntok + 1) * M_DIM;
    if (base >= n_tot) return;
    ushort4 o;
    if (base < n_real) {
        float4 v = *(const float4*)&x[base];
        o.x = f2bf(v.x); o.y = f2bf(v.y); o.z = f2bf(v.z); o.w = f2bf(v.w);
    } else {
        o.x = o.y = o.z = o.w = 0;
    }
    *(ushort4*)&xb[base] = o;
}

// ---------------------------------------------------------------------------
// Kernel 4: transpose+convert: src [E][R][C] fp32 -> dst [E][C][R] bf16
// grid (C/64, R/64, E), 256 threads.
// Write phase vectorized: each thread stores ushort4 (8B) along R so a wave
// emits 4x 128B contiguous segments instead of 64x 2B scattered stores.
// LDS read pattern (4*lx+cy+k) mod 32 is exactly 2-way -> conflict-free.
// ---------------------------------------------------------------------------
__global__ __launch_bounds__(256) void transpose_conv_kernel(const float* __restrict__ src,
                                                             unsigned short* __restrict__ dst,
                                                             int R, int C) {
    __shared__ float T[64][65];
    int e  = blockIdx.z;
    int c0 = blockIdx.x * 64;
    int r0 = blockIdx.y * 64;
    int tid = threadIdx.x;
    int lx = tid & 63, ly = tid >> 6;
    const float* Sp = src + (size_t)e * R * C;
#pragma unroll
    for (int i = 0; i < 16; ++i) {
        int r = i * 4 + ly;
        T[r][lx] = Sp[(size_t)(r0 + r) * C + c0 + lx];
    }
    __syncthreads();
    unsigned short* D = dst + (size_t)e * C * R;
    int rb = (tid & 15) * 4;   // base row of the 4 consecutive R-elements
    int cy = tid >> 4;         // 16 columns covered per pass
#pragma unroll
    for (int p = 0; p < 4; ++p) {
        int c = p * 16 + cy;
        ushort4 o;
        o.x = f2bf(T[rb + 0][c]);
        o.y = f2bf(T[rb + 1][c]);
        o.z = f2bf(T[rb + 2][c]);
        o.w = f2bf(T[rb + 3][c]);
        *(ushort4*)&D[(size_t)(c0 + c) * R + r0 + rb] = o;
    }
}

// ---------------------------------------------------------------------------
// Kernel 5: MFMA GEMM, 128x128 tile, BK=32, global_load_lds staging.
// A: [rows][KLEN] bf16 (optionally gathered via tfs); B: [n][KLEN] bf16.
// GATHER: A = x_bf16 (zero row at index zrow), out = h bf16 with relu.
// else:   A = h + z*CAP*KLEN, out = eo fp32.
//
// 1-D grid with XCD-chunked, reuse-ordered remap:
//   logical order (outer->inner): e, n0, g, c0
//   lid = (bid%8)*per + bid/8  => XCD k owns experts {2k, 2k+1} contiguously.
// The 4 blocks sharing one B n0-panel (2 c0 x 2 g) are consecutive on the
// SAME XCD -> B panel fetched once/expert; A tiles (<=3 MB) stay L2-hot
// across the n0 sweep.
// ---------------------------------------------------------------------------
template<int KLEN, bool GATHER>
__global__ __launch_bounds__(256) void mfma_gemm_kernel(
        const unsigned short* __restrict__ A,
        const unsigned short* __restrict__ B,
        const int* __restrict__ tfs,
        void* __restrict__ Out, int G, int N_total) {
    __shared__ unsigned short As[128 * 32];
    __shared__ unsigned short Bs[128 * 32];
    __shared__ int rowtok[128];

    // ---- block remap (bijective; NB % 8 == 0 for both GEMMs) ----
    int NB  = gridDim.x;
    int bid = blockIdx.x;
    int lid = bid;
    if ((NB & 7) == 0) {
        int per = NB >> 3;
        lid = (bid & 7) * per + (bid >> 3);
    }
    int NT_N = N_total >> 7;        // N_total / 128
    int c  = lid & 1;               // CAP/128 == 2
    int r1 = lid >> 1;
    int g  = r1 % G;
    int r2 = r1 / G;
    int n  = r2 % NT_N;
    int e  = r2 / NT_N;
    int z  = e * G + g;
    int n0 = n * 128;
    int c0 = c * 128;
    int tid = threadIdx.x;

    if (GATHER) {
        if (tid < 128) rowtok[tid] = tfs[((size_t)g * E_NUM + e) * CAP + c0 + tid];
        __syncthreads();
    }

    int r4 = tid >> 2, l4 = tid & 3;
    const unsigned short *apt0, *apt1;
    if (GATHER) {
        int t0 = rowtok[r4], t1 = rowtok[64 + r4];
        size_t row0 = (t0 < 0) ? (size_t)(G * S_TOK) : (size_t)(g * S_TOK + t0);
        size_t row1 = (t1 < 0) ? (size_t)(G * S_TOK) : (size_t)(g * S_TOK + t1);
        apt0 = A + row0 * KLEN + l4 * 8;
        apt1 = A + row1 * KLEN + l4 * 8;
    } else {
        apt0 = A + ((size_t)z * CAP + c0 + r4) * KLEN + l4 * 8;
        apt1 = apt0 + (size_t)64 * KLEN;
    }
    const unsigned short* Bexp = B + (size_t)e * N_total * KLEN;
    const unsigned short* bpt0 = Bexp + ((size_t)n0 + r4) * KLEN + l4 * 8;
    const unsigned short* bpt1 = bpt0 + (size_t)64 * KLEN;

    int wv = tid >> 6;
    unsigned short* as0 = &As[(wv * 16) * 32];
    unsigned short* as1 = &As[(64 + wv * 16) * 32];
    unsigned short* bs0 = &Bs[(wv * 16) * 32];
    unsigned short* bs1 = &Bs[(64 + wv * 16) * 32];

    int lane = tid & 63;
    int r = lane & 15, q = lane >> 4;
    int wm = wv & 1, wn = wv >> 1;

    f32x4 acc[4][4];
#pragma unroll
    for (int i = 0; i < 4; ++i)
#pragma unroll
        for (int j = 0; j < 4; ++j) acc[i][j] = (f32x4)(0.f);

    for (int k0 = 0; k0 < KLEN; k0 += 32) {
        async16(apt0, as0);
        async16(apt1, as1);
        async16(bpt0, bs0);
        async16(bpt1, bs1);
        apt0 += 32; apt1 += 32; bpt0 += 32; bpt1 += 32;
        __syncthreads();
        s16x8 af[4], bfr[4];
#pragma unroll
        for (int i = 0; i < 4; ++i)
            af[i] = *(const s16x8*)&As[(wm * 64 + i * 16 + r) * 32 + q * 8];
#pragma unroll
        for (int j = 0; j < 4; ++j)
            bfr[j] = *(const s16x8*)&Bs[(wn * 64 + j * 16 + r) * 32 + q * 8];
#pragma unroll
        for (int i = 0; i < 4; ++i)
#pragma unroll
            for (int j = 0; j < 4; ++j)
                acc[i][j] = __builtin_amdgcn_mfma_f32_16x16x32_bf16(af[i], bfr[j], acc[i][j], 0, 0, 0);
        __syncthreads();
    }

    // epilogue
    if (GATHER) {
        unsigned short* H = (unsigned short*)Out;   // [z][CAP][N_total]
#pragma unroll
        for (int i = 0; i < 4; ++i) {
#pragma unroll
            for (int v = 0; v < 4; ++v) {
                int m_loc = wm * 64 + i * 16 + q * 4 + v;
                unsigned short* row = H + ((size_t)z * CAP + c0 + m_loc) * N_total + n0;
#pragma unroll
                for (int j = 0; j < 4; ++j) {
                    int n_loc = wn * 64 + j * 16 + r;
                    row[n_loc] = f2bf(fmaxf(acc[i][j][v], 0.f));
                }
            }
        }
    } else {
        float* O = (float*)Out;                     // [(g*E+e)][CAP][N_total]
#pragma unroll
        for (int i = 0; i < 4; ++i) {
#pragma unroll
            for (int v = 0; v < 4; ++v) {
                int m_loc = wm * 64 + i * 16 + q * 4 + v;
                float* row = O + (((size_t)g * E_NUM + e) * CAP + c0 + m_loc) * N_total + n0;
#pragma unroll
                for (int j = 0; j < 4; ++j) {
                    int n_loc = wn * 64 + j * 16 + r;
                    row[n_loc] = acc[i][j][v];
                }
            }
        }
    }
}

// ---------------------------------------------------------------------------
// Kernel 6: combine — out[t,:] = w1*eo[g,slot1,:] + w2*eo[g,slot2,:]
// ---------------------------------------------------------------------------
__global__ void combine_kernel(const float* __restrict__ eo,
                               const int* __restrict__ slot1, const int* __restrict__ slot2,
                               const float* __restrict__ w1, const float* __restrict__ w2,
                               float* __restrict__ out, int G) {
    int t = blockIdx.x;
    int g = t / S_TOK;
    int tid = threadIdx.x;
    int s1 = slot1[t], s2 = slot2[t];
    float a = w1[t], b = w2[t];
    const float* base_g = eo + (size_t)g * E_NUM * CAP * M_DIM;
    const float* p1 = base_g + (size_t)(s1 < 0 ? 0 : s1) * M_DIM;
    const float* p2 = base_g + (size_t)(s2 < 0 ? 0 : s2) * M_DIM;
    for (int m = tid; m < M_DIM; m += 256) {
        float v = 0.f;
        if (s1 >= 0) v += a * p1[m];
        if (s2 >= 0) v += b * p2[m];
        out[(size_t)t * M_DIM + m] = v;
    }
}

// ---------------------------------------------------------------------------
extern "C" void kernel_launch(void* const* d_in, const int* in_sizes, int n_in,
                              void* d_out, int out_size, void* d_ws, size_t ws_size,
                              hipStream_t stream) {
    const float* x  = (const float*)d_in[0];
    const float* wg = (const float*)d_in[1];
    const float* wi = (const float*)d_in[2];
    const float* wo = (const float*)d_in[3];
    float* out = (float*)d_out;

    int ntok = in_sizes[0] / M_DIM;   // 4096
    int G = ntok / S_TOK;             // 2

    // workspace carve (256B aligned chunks)
    char* wsp = (char*)d_ws;
    auto carve = [&](size_t bytes) {
        void* p = (void*)wsp;
        wsp += (bytes + 255) & ~(size_t)255;
        return p;
    };
    int*   e1    = (int*)carve((size_t)ntok * 4);
    int*   e2    = (int*)carve((size_t)ntok * 4);
    float* g1    = (float*)carve((size_t)ntok * 4);
    float* g2    = (float*)carve((size_t)ntok * 4);
    int*   slot1 = (int*)carve((size_t)ntok * 4);
    int*   slot2 = (int*)carve((size_t)ntok * 4);
    float* w1    = (float*)carve((size_t)ntok * 4);
    float* w2    = (float*)carve((size_t)ntok * 4);
    int*   tfs   = (int*)carve((size_t)G * E_NUM * CAP * 4);
    unsigned short* xb  = (unsigned short*)carve((size_t)(ntok + 1) * M_DIM * 2);
    unsigned short* wiT = (unsigned short*)carve((size_t)E_NUM * H_DIM * M_DIM * 2);
    unsigned short* woT = (unsigned short*)carve((size_t)E_NUM * M_DIM * H_DIM * 2);
    unsigned short* h   = (unsigned short*)carve((size_t)E_NUM * G * CAP * H_DIM * 2);
    float* eo = (float*)carve((size_t)G * E_NUM * CAP * M_DIM * 4);

    gating_kernel<<<(ntok * 64 + 255) / 256, 256, 0, stream>>>(x, wg, e1, e2, g1, g2, ntok);
    assign_kernel<<<G, 1024, 0, stream>>>(e1, e2, g1, g2, slot1, slot2, w1, w2, tfs, G);

    int nx4 = ((ntok + 1) * M_DIM) / 4;
    convert_x_kernel<<<(nx4 + 255) / 256, 256, 0, stream>>>(x, xb, ntok);
    // wi [E][M][H] -> wiT [E][H][M]
    transpose_conv_kernel<<<dim3(H_DIM / 64, M_DIM / 64, E_NUM), 256, 0, stream>>>(wi, wiT, M_DIM, H_DIM);
    // wo [E][H][M] -> woT [E][M][H]
    transpose_conv_kernel<<<dim3(M_DIM / 64, H_DIM / 64, E_NUM), 256, 0, stream>>>(wo, woT, H_DIM, M_DIM);

    // gemm1: h[z][CAP][H] = relu(gather(xb) @ wiT^T), K=768   (1-D swizzled grid)
    mfma_gemm_kernel<M_DIM, true><<<(H_DIM / 128) * (CAP / 128) * E_NUM * G, 256, 0, stream>>>(
        xb, wiT, tfs, h, G, H_DIM);
    // gemm2: eo[(g*E+e)][CAP][M] = h @ woT^T, K=3072          (1-D swizzled grid)
    mfma_gemm_kernel<H_DIM, false><<<(M_DIM / 128) * (CAP / 128) * E_NUM * G, 256, 0, stream>>>(
        h, woT, tfs, eo, G, M_DIM);

    combine_kernel<<<ntok, 256, 0, stream>>>(eo, slot1, slot2, w1, w2, out, G);
}

// Round 3
// 535.541 us; speedup vs baseline: 1.0281x; 1.0215x over previous
//
#include <hip/hip_runtime.h>
#include <hip/hip_bf16.h>
#include <cstdint>
#include <cstddef>

#define S_TOK 2048
#define M_DIM 768
#define H_DIM 3072
#define E_NUM 16
#define CAP   256   // 2*S/E

using s16x8 = __attribute__((ext_vector_type(8))) short;  // 8 bf16 (4 VGPRs)
using f32x4 = __attribute__((ext_vector_type(4))) float;

__device__ __forceinline__ unsigned short f2bf(float f) {
    unsigned u = __float_as_uint(f);
    unsigned r = 0x7fffu + ((u >> 16) & 1u);
    return (unsigned short)((u + r) >> 16);
}

__device__ __forceinline__ void async16(const void* g, void* l) {
    __builtin_amdgcn_global_load_lds((const __attribute__((address_space(1))) void*)g,
                                     (__attribute__((address_space(3))) void*)l, 16, 0, 0);
}

// ---------------------------------------------------------------------------
// Kernel 1: gating — logits = x@wg, softmax, top1/top2 (one wave per token)
// ---------------------------------------------------------------------------
__global__ void gating_kernel(const float* __restrict__ x, const float* __restrict__ wg,
                              int* __restrict__ e1o, int* __restrict__ e2o,
                              float* __restrict__ g1o, float* __restrict__ g2o, int ntok) {
    int gid  = blockIdx.x * blockDim.x + threadIdx.x;
    int tok  = gid >> 6;
    int lane = threadIdx.x & 63;
    if (tok >= ntok) return;
    const float* xr = x + (size_t)tok * M_DIM;
    float acc[E_NUM];
#pragma unroll
    for (int e = 0; e < E_NUM; ++e) acc[e] = 0.f;
    for (int m = lane; m < M_DIM; m += 64) {
        float xv = xr[m];
        const float* wr = wg + (size_t)m * E_NUM;
#pragma unroll
        for (int e = 0; e < E_NUM; ++e) acc[e] += xv * wr[e];
    }
#pragma unroll
    for (int off = 32; off >= 1; off >>= 1) {
#pragma unroll
        for (int e = 0; e < E_NUM; ++e) acc[e] += __shfl_xor(acc[e], off, 64);
    }
    if (lane == 0) {
        float mx = acc[0];
#pragma unroll
        for (int e = 1; e < E_NUM; ++e) mx = fmaxf(mx, acc[e]);
        float p[E_NUM]; float s = 0.f;
#pragma unroll
        for (int e = 0; e < E_NUM; ++e) { p[e] = expf(acc[e] - mx); s += p[e]; }
        float inv = 1.f / s;
        int b1 = 0; float v1 = -1.f;
#pragma unroll
        for (int e = 0; e < E_NUM; ++e) { if (p[e] > v1) { v1 = p[e]; b1 = e; } }
        int b2 = 0; float v2 = -1.f;
#pragma unroll
        for (int e = 0; e < E_NUM; ++e) { if (e != b1 && p[e] > v2) { v2 = p[e]; b2 = e; } }
        e1o[tok] = b1; e2o[tok] = b2;
        g1o[tok] = v1 * inv; g2o[tok] = v2 * inv;
    }
}

// ---------------------------------------------------------------------------
// Kernel 2: assignment — capacity positions via ballot prefix scan.
// ---------------------------------------------------------------------------
__global__ void assign_kernel(const int* __restrict__ e1a, const int* __restrict__ e2a,
                              const float* __restrict__ g1a, const float* __restrict__ g2a,
                              int* __restrict__ slot1, int* __restrict__ slot2,
                              float* __restrict__ w1, float* __restrict__ w2,
                              int* __restrict__ tfs, int G) {
    int g    = blockIdx.x;
    int tid  = threadIdx.x;
    int w    = tid >> 6;
    int lane = tid & 63;
    __shared__ int cnt1s[E_NUM];

    for (int i = tid; i < E_NUM * CAP; i += 1024) tfs[(size_t)g * E_NUM * CAP + i] = -1;
    __syncthreads();

    {
        int cnt = 0;
        for (int base = 0; base < S_TOK; base += 64) {
            int t = g * S_TOK + base + lane;
            bool pred = (e1a[t] == w);
            unsigned long long bal = __ballot(pred);
            int prefix = __popcll(bal & ((1ull << lane) - 1ull));
            if (pred) {
                int pos = cnt + prefix;
                if (pos < CAP) {
                    slot1[t] = w * CAP + pos;
                    tfs[((size_t)g * E_NUM + w) * CAP + pos] = base + lane;
                } else {
                    slot1[t] = -1;
                }
            }
            cnt += __popcll(bal);
        }
        if (lane == 0) cnt1s[w] = cnt < CAP ? cnt : CAP;
    }
    __syncthreads();
    {
        int cnt = cnt1s[w];
        for (int base = 0; base < S_TOK; base += 64) {
            int t = g * S_TOK + base + lane;
            bool pred = (e2a[t] == w);
            unsigned long long bal = __ballot(pred);
            int prefix = __popcll(bal & ((1ull << lane) - 1ull));
            if (pred) {
                int pos = cnt + prefix;
                if (pos < CAP) {
                    slot2[t] = w * CAP + pos;
                    tfs[((size_t)g * E_NUM + w) * CAP + pos] = base + lane;
                } else {
                    slot2[t] = -1;
                }
            }
            cnt += __popcll(bal);
        }
    }
    __syncthreads();
    for (int t = tid; t < S_TOK; t += 1024) {
        int gt = g * S_TOK + t;
        float a = slot1[gt] >= 0 ? g1a[gt] : 0.f;
        float b = slot2[gt] >= 0 ? g2a[gt] : 0.f;
        float denom = a + b;
        if (!(denom > 0.f)) denom = 1.f;
        w1[gt] = a / denom;
        w2[gt] = b / denom;
    }
}

// ---------------------------------------------------------------------------
// Kernel 3: x fp32 -> bf16, plus one zero row appended at row ntok
// ---------------------------------------------------------------------------
__global__ void convert_x_kernel(const float* __restrict__ x, unsigned short* __restrict__ xb,
                                 int ntok) {
    int i4 = blockIdx.x * blockDim.x + threadIdx.x;
    size_t base = (size_t)i4 * 4;
    size_t n_real = (size_t)ntok * M_DIM;
    size_t n_tot  = (size_t)(ntok + 1) * M_DIM;
    if (base >= n_tot) return;
    ushort4 o;
    if (base < n_real) {
        float4 v = *(const float4*)&x[base];
        o.x = f2bf(v.x); o.y = f2bf(v.y); o.z = f2bf(v.z); o.w = f2bf(v.w);
    } else {
        o.x = o.y = o.z = o.w = 0;
    }
    *(ushort4*)&xb[base] = o;
}

// ---------------------------------------------------------------------------
// Kernel 4: transpose+convert: src [E][R][C] fp32 -> dst [E][C][R] bf16
// ---------------------------------------------------------------------------
__global__ __launch_bounds__(256) void transpose_conv_kernel(const float* __restrict__ src,
                                                             unsigned short* __restrict__ dst,
                                                             int R, int C) {
    __shared__ float T[64][65];
    int e  = blockIdx.z;
    int c0 = blockIdx.x * 64;
    int r0 = blockIdx.y * 64;
    int tid = threadIdx.x;
    int lx = tid & 63, ly = tid >> 6;
    const float* Sp = src + (size_t)e * R * C;
#pragma unroll
    for (int i = 0; i < 16; ++i) {
        int r = i * 4 + ly;
        T[r][lx] = Sp[(size_t)(r0 + r) * C + c0 + lx];
    }
    __syncthreads();
    unsigned short* D = dst + (size_t)e * C * R;
    int rb = (tid & 15) * 4;   // base row of the 4 consecutive R-elements
    int cy = tid >> 4;         // 16 columns covered per pass
#pragma unroll
    for (int p = 0; p < 4; ++p) {
        int c = p * 16 + cy;
        ushort4 o;
        o.x = f2bf(T[rb + 0][c]);
        o.y = f2bf(T[rb + 1][c]);
        o.z = f2bf(T[rb + 2][c]);
        o.w = f2bf(T[rb + 3][c]);
        *(ushort4*)&D[(size_t)(c0 + c) * R + r0 + rb] = o;
    }
}

// ---------------------------------------------------------------------------
// Kernel 5: MFMA GEMM, 128x128 tile, BK=32, DOUBLE-BUFFERED pipeline:
//   stage tile t+1 into buf^1 BEFORE computing tile t; one barrier/iter.
// __syncthreads() semantics (vmcnt(0) drain before s_barrier) make the dbuf
// race-free: a buffer is only restaged after the barrier that follows the
// phase which read it.
//
// Grid: 1-D, XCD-chunked remap; logical order (outer->inner): e, kh, n, g, c.
// NKH = K-split factor (1 for gemm1, 2 for gemm2); half kh writes Out0/Out1.
// ---------------------------------------------------------------------------
template<int KLOOP, bool GATHER>
__global__ __launch_bounds__(256) void mfma_gemm_kernel(
        const unsigned short* __restrict__ A,
        const unsigned short* __restrict__ B,
        const int* __restrict__ tfs,
        void* __restrict__ Out0, void* __restrict__ Out1,
        int G, int N_total, int kstride, int NKH) {
    __shared__ unsigned short As[2][128 * 32];
    __shared__ unsigned short Bs[2][128 * 32];
    __shared__ int rowtok[128];

    // ---- block remap (bijective; NB % 8 == 0 for both GEMMs) ----
    int NB  = gridDim.x;
    int bid = blockIdx.x;
    int per = NB >> 3;
    int lid = (bid & 7) * per + (bid >> 3);

    int NT_N = N_total >> 7;        // N_total / 128
    int c  = lid & 1;               // CAP/128 == 2
    int r1 = lid >> 1;
    int g  = r1 % G;
    int r2 = r1 / G;
    int n  = r2 % NT_N;
    int r3 = r2 / NT_N;
    int kh = r3 % NKH;
    int e  = r3 / NKH;
    int z  = e * G + g;
    int n0 = n * 128;
    int c0 = c * 128;
    int koff = kh * KLOOP;
    int tid = threadIdx.x;

    if (GATHER) {
        if (tid < 128) rowtok[tid] = tfs[((size_t)g * E_NUM + e) * CAP + c0 + tid];
        __syncthreads();
    }

    int r4 = tid >> 2, l4 = tid & 3;
    const unsigned short *apt0, *apt1;
    if (GATHER) {
        int t0 = rowtok[r4], t1 = rowtok[64 + r4];
        size_t row0 = (t0 < 0) ? (size_t)(G * S_TOK) : (size_t)(g * S_TOK + t0);
        size_t row1 = (t1 < 0) ? (size_t)(G * S_TOK) : (size_t)(g * S_TOK + t1);
        apt0 = A + row0 * kstride + koff + l4 * 8;
        apt1 = A + row1 * kstride + koff + l4 * 8;
    } else {
        apt0 = A + ((size_t)z * CAP + c0 + r4) * kstride + koff + l4 * 8;
        apt1 = apt0 + (size_t)64 * kstride;
    }
    const unsigned short* Bexp = B + (size_t)e * N_total * kstride;
    const unsigned short* bpt0 = Bexp + ((size_t)n0 + r4) * kstride + koff + l4 * 8;
    const unsigned short* bpt1 = bpt0 + (size_t)64 * kstride;

    int wv = tid >> 6;
    int lane = tid & 63;
    int r = lane & 15, q = lane >> 4;
    int wm = wv & 1, wn = wv >> 1;

    f32x4 acc[4][4];
#pragma unroll
    for (int i = 0; i < 4; ++i)
#pragma unroll
        for (int j = 0; j < 4; ++j) acc[i][j] = (f32x4)(0.f);

#define STAGE(b) do {                                    \
        async16(apt0, &As[b][(wv * 16) * 32]);           \
        async16(apt1, &As[b][(64 + wv * 16) * 32]);      \
        async16(bpt0, &Bs[b][(wv * 16) * 32]);           \
        async16(bpt1, &Bs[b][(64 + wv * 16) * 32]);      \
        apt0 += 32; apt1 += 32; bpt0 += 32; bpt1 += 32;  \
    } while (0)

    const int NT = KLOOP / 32;
    STAGE(0);
    __syncthreads();          // tile 0 resident
    int cur = 0;
    for (int t = 0; t < NT; ++t) {
        if (t + 1 < NT) STAGE(cur ^ 1);   // issue next tile early; latency hides under compute
        s16x8 af[4], bfr[4];
#pragma unroll
        for (int i = 0; i < 4; ++i)
            af[i] = *(const s16x8*)&As[cur][(wm * 64 + i * 16 + r) * 32 + q * 8];
#pragma unroll
        for (int j = 0; j < 4; ++j)
            bfr[j] = *(const s16x8*)&Bs[cur][(wn * 64 + j * 16 + r) * 32 + q * 8];
#pragma unroll
        for (int i = 0; i < 4; ++i)
#pragma unroll
            for (int j = 0; j < 4; ++j)
                acc[i][j] = __builtin_amdgcn_mfma_f32_16x16x32_bf16(af[i], bfr[j], acc[i][j], 0, 0, 0);
        __syncthreads();      // next tile resident; cur buffer free for restage
        cur ^= 1;
    }
#undef STAGE

    // epilogue
    if (GATHER) {
        unsigned short* H = (unsigned short*)Out0;  // [z][CAP][N_total]
#pragma unroll
        for (int i = 0; i < 4; ++i) {
#pragma unroll
            for (int v = 0; v < 4; ++v) {
                int m_loc = wm * 64 + i * 16 + q * 4 + v;
                unsigned short* row = H + ((size_t)z * CAP + c0 + m_loc) * N_total + n0;
#pragma unroll
                for (int j = 0; j < 4; ++j) {
                    int n_loc = wn * 64 + j * 16 + r;
                    row[n_loc] = f2bf(fmaxf(acc[i][j][v], 0.f));
                }
            }
        }
    } else {
        float* O = (float*)(kh ? Out1 : Out0);      // [(g*E+e)][CAP][N_total]
#pragma unroll
        for (int i = 0; i < 4; ++i) {
#pragma unroll
            for (int v = 0; v < 4; ++v) {
                int m_loc = wm * 64 + i * 16 + q * 4 + v;
                float* row = O + (((size_t)g * E_NUM + e) * CAP + c0 + m_loc) * N_total + n0;
#pragma unroll
                for (int j = 0; j < 4; ++j) {
                    int n_loc = wn * 64 + j * 16 + r;
                    row[n_loc] = acc[i][j][v];
                }
            }
        }
    }
}

// ---------------------------------------------------------------------------
// Kernel 6: combine — out[t,:] = w1*(eoA+eoB)[g,slot1,:] + w2*(eoA+eoB)[g,slot2,:]
// ---------------------------------------------------------------------------
__global__ void combine_kernel(const float* __restrict__ eoA, const float* __restrict__ eoB,
                               const int* __restrict__ slot1, const int* __restrict__ slot2,
                               const float* __restrict__ w1, const float* __restrict__ w2,
                               float* __restrict__ out, int G) {
    int t = blockIdx.x;
    int g = t / S_TOK;
    int tid = threadIdx.x;
    int s1 = slot1[t], s2 = slot2[t];
    float a = w1[t], b = w2[t];
    size_t gb = (size_t)g * E_NUM * CAP * M_DIM;
    const float* p1A = eoA + gb + (size_t)(s1 < 0 ? 0 : s1) * M_DIM;
    const float* p1B = eoB + gb + (size_t)(s1 < 0 ? 0 : s1) * M_DIM;
    const float* p2A = eoA + gb + (size_t)(s2 < 0 ? 0 : s2) * M_DIM;
    const float* p2B = eoB + gb + (size_t)(s2 < 0 ? 0 : s2) * M_DIM;
    for (int m = tid; m < M_DIM; m += 256) {
        float v = 0.f;
        if (s1 >= 0) v += a * (p1A[m] + p1B[m]);
        if (s2 >= 0) v += b * (p2A[m] + p2B[m]);
        out[(size_t)t * M_DIM + m] = v;
    }
}

// ---------------------------------------------------------------------------
extern "C" void kernel_launch(void* const* d_in, const int* in_sizes, int n_in,
                              void* d_out, int out_size, void* d_ws, size_t ws_size,
                              hipStream_t stream) {
    const float* x  = (const float*)d_in[0];
    const float* wg = (const float*)d_in[1];
    const float* wi = (const float*)d_in[2];
    const float* wo = (const float*)d_in[3];
    float* out = (float*)d_out;

    int ntok = in_sizes[0] / M_DIM;   // 4096
    int G = ntok / S_TOK;             // 2

    // workspace carve (256B aligned chunks)
    char* wsp = (char*)d_ws;
    auto carve = [&](size_t bytes) {
        void* p = (void*)wsp;
        wsp += (bytes + 255) & ~(size_t)255;
        return p;
    };
    int*   e1    = (int*)carve((size_t)ntok * 4);
    int*   e2    = (int*)carve((size_t)ntok * 4);
    float* g1    = (float*)carve((size_t)ntok * 4);
    float* g2    = (float*)carve((size_t)ntok * 4);
    int*   slot1 = (int*)carve((size_t)ntok * 4);
    int*   slot2 = (int*)carve((size_t)ntok * 4);
    float* w1    = (float*)carve((size_t)ntok * 4);
    float* w2    = (float*)carve((size_t)ntok * 4);
    int*   tfs   = (int*)carve((size_t)G * E_NUM * CAP * 4);
    unsigned short* xb  = (unsigned short*)carve((size_t)(ntok + 1) * M_DIM * 2);
    unsigned short* wiT = (unsigned short*)carve((size_t)E_NUM * H_DIM * M_DIM * 2);
    unsigned short* woT = (unsigned short*)carve((size_t)E_NUM * M_DIM * H_DIM * 2);
    unsigned short* h   = (unsigned short*)carve((size_t)E_NUM * G * CAP * H_DIM * 2);
    float* eo = (float*)carve((size_t)G * E_NUM * CAP * M_DIM * 4);
    // eoB (split-K half 2 of gemm2) aliases wiT: wiT is dead after gemm1, and
    // wiT (75.5 MB) > eoB (25.2 MB).  Zero workspace growth.
    float* eoB = (float*)wiT;

    gating_kernel<<<(ntok * 64 + 255) / 256, 256, 0, stream>>>(x, wg, e1, e2, g1, g2, ntok);
    assign_kernel<<<G, 1024, 0, stream>>>(e1, e2, g1, g2, slot1, slot2, w1, w2, tfs, G);

    int nx4 = ((ntok + 1) * M_DIM) / 4;
    convert_x_kernel<<<(nx4 + 255) / 256, 256, 0, stream>>>(x, xb, ntok);
    // wi [E][M][H] -> wiT [E][H][M]
    transpose_conv_kernel<<<dim3(H_DIM / 64, M_DIM / 64, E_NUM), 256, 0, stream>>>(wi, wiT, M_DIM, H_DIM);
    // wo [E][H][M] -> woT [E][M][H]
    transpose_conv_kernel<<<dim3(M_DIM / 64, H_DIM / 64, E_NUM), 256, 0, stream>>>(wo, woT, H_DIM, M_DIM);

    // gemm1: h[z][CAP][H] = relu(gather(xb) @ wiT^T), K=768, no K-split
    mfma_gemm_kernel<M_DIM, true><<<(H_DIM / 128) * (CAP / 128) * E_NUM * G, 256, 0, stream>>>(
        xb, wiT, tfs, h, h, G, H_DIM, M_DIM, 1);
    // gemm2: eo(+eoB)[(g*E+e)][CAP][M] = h @ woT^T, K=3072 split into 2x1536
    //        768 blocks -> 3 blocks/CU (was 384 -> 1.5, half-idle tail round)
    mfma_gemm_kernel<H_DIM / 2, false><<<(M_DIM / 128) * (CAP / 128) * E_NUM * G * 2, 256, 0, stream>>>(
        h, woT, tfs, eo, eoB, G, M_DIM, H_DIM, 2);

    combine_kernel<<<ntok, 256, 0, stream>>>(eo, eoB, slot1, slot2, w1, w2, out, G);
}

// Round 5
// 534.424 us; speedup vs baseline: 1.0303x; 1.0021x over previous
//
#include <hip/hip_runtime.h>
#include <hip/hip_bf16.h>
#include <cstdint>
#include <cstddef>

#define S_TOK 2048
#define M_DIM 768
#define H_DIM 3072
#define E_NUM 16
#define CAP   256   // 2*S/E

using s16x8 = __attribute__((ext_vector_type(8))) short;  // 8 bf16 (4 VGPRs)
using f32x4 = __attribute__((ext_vector_type(4))) float;

__device__ __forceinline__ unsigned short f2bf(float f) {
    unsigned u = __float_as_uint(f);
    unsigned r = 0x7fffu + ((u >> 16) & 1u);
    return (unsigned short)((u + r) >> 16);
}

__device__ __forceinline__ void async16(const void* g, void* l) {
    __builtin_amdgcn_global_load_lds((const __attribute__((address_space(1))) void*)g,
                                     (__attribute__((address_space(3))) void*)l, 16, 0, 0);
}

// ---------------------------------------------------------------------------
// Kernel 1: gating + x->bf16 conversion fused (one wave per token).
// Wave tok==ntok only writes the bf16 zero row.
// ---------------------------------------------------------------------------
__global__ void gating_kernel(const float* __restrict__ x, const float* __restrict__ wg,
                              int* __restrict__ e1o, int* __restrict__ e2o,
                              float* __restrict__ g1o, float* __restrict__ g2o,
                              unsigned short* __restrict__ xb, int ntok) {
    int gid  = blockIdx.x * blockDim.x + threadIdx.x;
    int tok  = gid >> 6;
    int lane = threadIdx.x & 63;
    if (tok > ntok) return;
    unsigned short* xbr = xb + (size_t)tok * M_DIM;
    if (tok == ntok) {                       // appended zero row
        for (int m = lane; m < M_DIM; m += 64) xbr[m] = 0;
        return;
    }
    const float* xr = x + (size_t)tok * M_DIM;
    float acc[E_NUM];
#pragma unroll
    for (int e = 0; e < E_NUM; ++e) acc[e] = 0.f;
    for (int m = lane; m < M_DIM; m += 64) {
        float xv = xr[m];
        xbr[m] = f2bf(xv);                   // fused conversion
        const float* wr = wg + (size_t)m * E_NUM;
#pragma unroll
        for (int e = 0; e < E_NUM; ++e) acc[e] += xv * wr[e];
    }
#pragma unroll
    for (int off = 32; off >= 1; off >>= 1) {
#pragma unroll
        for (int e = 0; e < E_NUM; ++e) acc[e] += __shfl_xor(acc[e], off, 64);
    }
    if (lane == 0) {
        float mx = acc[0];
#pragma unroll
        for (int e = 1; e < E_NUM; ++e) mx = fmaxf(mx, acc[e]);
        float p[E_NUM]; float s = 0.f;
#pragma unroll
        for (int e = 0; e < E_NUM; ++e) { p[e] = expf(acc[e] - mx); s += p[e]; }
        float inv = 1.f / s;
        int b1 = 0; float v1 = -1.f;
#pragma unroll
        for (int e = 0; e < E_NUM; ++e) { if (p[e] > v1) { v1 = p[e]; b1 = e; } }
        int b2 = 0; float v2 = -1.f;
#pragma unroll
        for (int e = 0; e < E_NUM; ++e) { if (e != b1 && p[e] > v2) { v2 = p[e]; b2 = e; } }
        e1o[tok] = b1; e2o[tok] = b2;
        g1o[tok] = v1 * inv; g2o[tok] = v2 * inv;
    }
}

// ---------------------------------------------------------------------------
// Kernel 2: assignment — capacity positions via ballot prefix scan.
// ---------------------------------------------------------------------------
__global__ void assign_kernel(const int* __restrict__ e1a, const int* __restrict__ e2a,
                              const float* __restrict__ g1a, const float* __restrict__ g2a,
                              int* __restrict__ slot1, int* __restrict__ slot2,
                              float* __restrict__ w1, float* __restrict__ w2,
                              int* __restrict__ tfs, int G) {
    int g    = blockIdx.x;
    int tid  = threadIdx.x;
    int w    = tid >> 6;
    int lane = tid & 63;
    __shared__ int cnt1s[E_NUM];

    for (int i = tid; i < E_NUM * CAP; i += 1024) tfs[(size_t)g * E_NUM * CAP + i] = -1;
    __syncthreads();

    {
        int cnt = 0;
        for (int base = 0; base < S_TOK; base += 64) {
            int t = g * S_TOK + base + lane;
            bool pred = (e1a[t] == w);
            unsigned long long bal = __ballot(pred);
            int prefix = __popcll(bal & ((1ull << lane) - 1ull));
            if (pred) {
                int pos = cnt + prefix;
                if (pos < CAP) {
                    slot1[t] = w * CAP + pos;
                    tfs[((size_t)g * E_NUM + w) * CAP + pos] = base + lane;
                } else {
                    slot1[t] = -1;
                }
            }
            cnt += __popcll(bal);
        }
        if (lane == 0) cnt1s[w] = cnt < CAP ? cnt : CAP;
    }
    __syncthreads();
    {
        int cnt = cnt1s[w];
        for (int base = 0; base < S_TOK; base += 64) {
            int t = g * S_TOK + base + lane;
            bool pred = (e2a[t] == w);
            unsigned long long bal = __ballot(pred);
            int prefix = __popcll(bal & ((1ull << lane) - 1ull));
            if (pred) {
                int pos = cnt + prefix;
                if (pos < CAP) {
                    slot2[t] = w * CAP + pos;
                    tfs[((size_t)g * E_NUM + w) * CAP + pos] = base + lane;
                } else {
                    slot2[t] = -1;
                }
            }
            cnt += __popcll(bal);
        }
    }
    __syncthreads();
    for (int t = tid; t < S_TOK; t += 1024) {
        int gt = g * S_TOK + t;
        float a = slot1[gt] >= 0 ? g1a[gt] : 0.f;
        float b = slot2[gt] >= 0 ? g2a[gt] : 0.f;
        float denom = a + b;
        if (!(denom > 0.f)) denom = 1.f;
        w1[gt] = a / denom;
        w2[gt] = b / denom;
    }
}

// ---------------------------------------------------------------------------
// Kernel 3: fused transpose+convert for BOTH weights in one launch.
// wi [E][768][3072] -> wiT [E][3072][768]; wo [E][3072][768] -> woT [E][768][3072]
// 1-D grid: first NB_WI blocks handle wi, rest handle wo.
// ---------------------------------------------------------------------------
#define NB_WI ((H_DIM / 64) * (M_DIM / 64) * E_NUM)   // 48*12*16 = 9216
__global__ __launch_bounds__(256) void transpose_conv_kernel(const float* __restrict__ wi,
                                                             unsigned short* __restrict__ wiT,
                                                             const float* __restrict__ wo,
                                                             unsigned short* __restrict__ woT) {
    __shared__ float T[64][65];
    int bid = blockIdx.x;
    const float* src; unsigned short* dst; int R, C, cx, ry, e;
    if (bid < NB_WI) {
        int per = (H_DIM / 64) * (M_DIM / 64);   // 576
        e = bid / per; int rem = bid % per;
        cx = rem % (H_DIM / 64); ry = rem / (H_DIM / 64);
        R = M_DIM; C = H_DIM; src = wi; dst = wiT;
    } else {
        int b2 = bid - NB_WI;
        int per = (M_DIM / 64) * (H_DIM / 64);
        e = b2 / per; int rem = b2 % per;
        cx = rem % (M_DIM / 64); ry = rem / (M_DIM / 64);
        R = H_DIM; C = M_DIM; src = wo; dst = woT;
    }
    int c0 = cx * 64;
    int r0 = ry * 64;
    int tid = threadIdx.x;
    int lx = tid & 63, ly = tid >> 6;
    const float* Sp = src + (size_t)e * R * C;
#pragma unroll
    for (int i = 0; i < 16; ++i) {
        int r = i * 4 + ly;
        T[r][lx] = Sp[(size_t)(r0 + r) * C + c0 + lx];
    }
    __syncthreads();
    unsigned short* D = dst + (size_t)e * C * R;
    int rb = (tid & 15) * 4;
    int cy = tid >> 4;
#pragma unroll
    for (int p = 0; p < 4; ++p) {
        int c = p * 16 + cy;
        ushort4 o;
        o.x = f2bf(T[rb + 0][c]);
        o.y = f2bf(T[rb + 1][c]);
        o.z = f2bf(T[rb + 2][c]);
        o.w = f2bf(T[rb + 3][c]);
        *(ushort4*)&D[(size_t)(c0 + c) * R + r0 + rb] = o;
    }
}

// ---------------------------------------------------------------------------
// Kernel 5: MFMA GEMM, 256x128 tile (M = full CAP), BK=32, 512 threads/8 waves,
// double-buffered (stage t+1 before computing t, one barrier per iter).
// Wave grid 2M x 4N: per-wave output 128x32 -> acc[8][2] f32x4 (64 VGPR).
//
// Grid 1-D, XCD-chunked remap; logical order (outer->inner): e, kh, n, g.
// ---------------------------------------------------------------------------
template<int KLOOP, bool GATHER>
__global__ __launch_bounds__(512, 4) void mfma_gemm_kernel(
        const unsigned short* __restrict__ A,
        const unsigned short* __restrict__ B,
        const int* __restrict__ tfs,
        void* __restrict__ Out0, void* __restrict__ Out1,
        int G, int N_total, int kstride, int NKH) {
    __shared__ unsigned short As[2][256 * 32];   // 32 KB
    __shared__ unsigned short Bs[2][128 * 32];   // 16 KB
    __shared__ int rowtok[256];

    // ---- block remap (bijective; NB % 8 == 0) ----
    int NB  = gridDim.x;
    int bid = blockIdx.x;
    int per = NB >> 3;
    int lid = (bid & 7) * per + (bid >> 3);

    int NT_N = N_total >> 7;        // n-tiles of 128
    int g  = lid % G;
    int r1 = lid / G;
    int n  = r1 % NT_N;
    int r2 = r1 / NT_N;
    int kh = r2 % NKH;
    int e  = r2 / NKH;
    int z  = e * G + g;
    int n0 = n * 128;
    int koff = kh * KLOOP;
    int tid = threadIdx.x;

    if (GATHER) {
        if (tid < 256) rowtok[tid] = tfs[((size_t)g * E_NUM + e) * CAP + tid];
        __syncthreads();
    }

    int r8 = tid >> 2, l4 = tid & 3;    // r8: 0..127 staging row, l4: 16B chunk
    const unsigned short *apt0, *apt1, *bpt0;
    if (GATHER) {
        int t0 = rowtok[r8], t1 = rowtok[128 + r8];
        size_t row0 = (t0 < 0) ? (size_t)(G * S_TOK) : (size_t)(g * S_TOK + t0);
        size_t row1 = (t1 < 0) ? (size_t)(G * S_TOK) : (size_t)(g * S_TOK + t1);
        apt0 = A + row0 * kstride + koff + l4 * 8;
        apt1 = A + row1 * kstride + koff + l4 * 8;
    } else {
        apt0 = A + ((size_t)z * CAP + r8) * kstride + koff + l4 * 8;
        apt1 = apt0 + (size_t)128 * kstride;
    }
    bpt0 = B + ((size_t)e * N_total + n0 + r8) * kstride + koff + l4 * 8;

    int wv = tid >> 6;                  // 0..7
    int lane = tid & 63;
    int r = lane & 15, q = lane >> 4;
    int wm = wv & 1, wn = wv >> 1;      // 2M x 4N

    f32x4 acc[8][2];
#pragma unroll
    for (int i = 0; i < 8; ++i) {
        acc[i][0] = (f32x4)(0.f);
        acc[i][1] = (f32x4)(0.f);
    }

#define STAGE(b) do {                                      \
        async16(apt0, &As[b][(wv * 16) * 32]);             \
        async16(apt1, &As[b][(128 + wv * 16) * 32]);       \
        async16(bpt0, &Bs[b][(wv * 16) * 32]);             \
        apt0 += 32; apt1 += 32; bpt0 += 32;                \
    } while (0)

    const int NT = KLOOP / 32;
    STAGE(0);
    __syncthreads();          // tile 0 resident
    int cur = 0;
    for (int t = 0; t < NT; ++t) {
        if (t + 1 < NT) STAGE(cur ^ 1);     // issue next tile; hides under compute
        s16x8 bfr0 = *(const s16x8*)&Bs[cur][(wn * 32 + r) * 32 + q * 8];
        s16x8 bfr1 = *(const s16x8*)&Bs[cur][(wn * 32 + 16 + r) * 32 + q * 8];
#pragma unroll
        for (int i = 0; i < 8; ++i) {
            s16x8 af = *(const s16x8*)&As[cur][(wm * 128 + i * 16 + r) * 32 + q * 8];
            acc[i][0] = __builtin_amdgcn_mfma_f32_16x16x32_bf16(af, bfr0, acc[i][0], 0, 0, 0);
            acc[i][1] = __builtin_amdgcn_mfma_f32_16x16x32_bf16(af, bfr1, acc[i][1], 0, 0, 0);
        }
        __syncthreads();      // next tile resident; cur buffer free for restage
        cur ^= 1;
    }
#undef STAGE

    // epilogue
    if (GATHER) {
        unsigned short* H = (unsigned short*)Out0;  // [z][CAP][N_total]
#pragma unroll
        for (int i = 0; i < 8; ++i) {
#pragma unroll
            for (int v = 0; v < 4; ++v) {
                int m_loc = wm * 128 + i * 16 + q * 4 + v;
                unsigned short* row = H + ((size_t)z * CAP + m_loc) * N_total + n0 + wn * 32;
#pragma unroll
                for (int j = 0; j < 2; ++j) {
                    row[j * 16 + r] = f2bf(fmaxf(acc[i][j][v], 0.f));
                }
            }
        }
    } else {
        float* O = (float*)(kh ? Out1 : Out0);      // [(g*E+e)][CAP][N_total]
#pragma unroll
        for (int i = 0; i < 8; ++i) {
#pragma unroll
            for (int v = 0; v < 4; ++v) {
                int m_loc = wm * 128 + i * 16 + q * 4 + v;
                float* row = O + (((size_t)g * E_NUM + e) * CAP + m_loc) * N_total + n0 + wn * 32;
#pragma unroll
                for (int j = 0; j < 2; ++j) {
                    row[j * 16 + r] = acc[i][j][v];
                }
            }
        }
    }
}

// ---------------------------------------------------------------------------
// Kernel 6: combine — out[t,:] = w1*(eoA+eoB)[g,slot1,:] + w2*(eoA+eoB)[g,slot2,:]
// ---------------------------------------------------------------------------
__global__ void combine_kernel(const float* __restrict__ eoA, const float* __restrict__ eoB,
                               const int* __restrict__ slot1, const int* __restrict__ slot2,
                               const float* __restrict__ w1, const float* __restrict__ w2,
                               float* __restrict__ out, int G) {
    int t = blockIdx.x;
    int g = t / S_TOK;
    int tid = threadIdx.x;
    int s1 = slot1[t], s2 = slot2[t];
    float a = w1[t], b = w2[t];
    size_t gb = (size_t)g * E_NUM * CAP * M_DIM;
    const float* p1A = eoA + gb + (size_t)(s1 < 0 ? 0 : s1) * M_DIM;
    const float* p1B = eoB + gb + (size_t)(s1 < 0 ? 0 : s1) * M_DIM;
    const float* p2A = eoA + gb + (size_t)(s2 < 0 ? 0 : s2) * M_DIM;
    const float* p2B = eoB + gb + (size_t)(s2 < 0 ? 0 : s2) * M_DIM;
    for (int m = tid; m < M_DIM; m += 256) {
        float v = 0.f;
        if (s1 >= 0) v += a * (p1A[m] + p1B[m]);
        if (s2 >= 0) v += b * (p2A[m] + p2B[m]);
        out[(size_t)t * M_DIM + m] = v;
    }
}

// ---------------------------------------------------------------------------
extern "C" void kernel_launch(void* const* d_in, const int* in_sizes, int n_in,
                              void* d_out, int out_size, void* d_ws, size_t ws_size,
                              hipStream_t stream) {
    const float* x  = (const float*)d_in[0];
    const float* wg = (const float*)d_in[1];
    const float* wi = (const float*)d_in[2];
    const float* wo = (const float*)d_in[3];
    float* out = (float*)d_out;

    int ntok = in_sizes[0] / M_DIM;   // 4096
    int G = ntok / S_TOK;             // 2

    // workspace carve (256B aligned chunks)
    char* wsp = (char*)d_ws;
    auto carve = [&](size_t bytes) {
        void* p = (void*)wsp;
        wsp += (bytes + 255) & ~(size_t)255;
        return p;
    };
    int*   e1    = (int*)carve((size_t)ntok * 4);
    int*   e2    = (int*)carve((size_t)ntok * 4);
    float* g1    = (float*)carve((size_t)ntok * 4);
    float* g2    = (float*)carve((size_t)ntok * 4);
    int*   slot1 = (int*)carve((size_t)ntok * 4);
    int*   slot2 = (int*)carve((size_t)ntok * 4);
    float* w1    = (float*)carve((size_t)ntok * 4);
    float* w2    = (float*)carve((size_t)ntok * 4);
    int*   tfs   = (int*)carve((size_t)G * E_NUM * CAP * 4);
    unsigned short* xb  = (unsigned short*)carve((size_t)(ntok + 1) * M_DIM * 2);
    unsigned short* wiT = (unsigned short*)carve((size_t)E_NUM * H_DIM * M_DIM * 2);
    unsigned short* woT = (unsigned short*)carve((size_t)E_NUM * M_DIM * H_DIM * 2);
    unsigned short* h   = (unsigned short*)carve((size_t)E_NUM * G * CAP * H_DIM * 2);
    float* eo = (float*)carve((size_t)G * E_NUM * CAP * M_DIM * 4);
    // eoB (split-K half 2 of gemm2) aliases wiT: dead after gemm1; 75.5 > 25.2 MB.
    float* eoB = (float*)wiT;

    // 1: gating + x conversion (ntok+1 waves)
    gating_kernel<<<((ntok + 1) * 64 + 255) / 256, 256, 0, stream>>>(
        x, wg, e1, e2, g1, g2, xb, ntok);
    // 2: assignment
    assign_kernel<<<G, 1024, 0, stream>>>(e1, e2, g1, g2, slot1, slot2, w1, w2, tfs, G);
    // 3: both weight transposes in one launch
    transpose_conv_kernel<<<2 * NB_WI, 256, 0, stream>>>(wi, wiT, wo, woT);

    // 4: gemm1: h[z][CAP][H] = relu(gather(xb) @ wiT^T), K=768, 256x128 tiles
    mfma_gemm_kernel<M_DIM, true><<<(H_DIM / 128) * E_NUM * G, 512, 0, stream>>>(
        xb, wiT, tfs, h, h, G, H_DIM, M_DIM, 1);
    // 5: gemm2: eo(+eoB) = h @ woT^T, K=3072 split 2x1536, 256x128 tiles
    mfma_gemm_kernel<H_DIM / 2, false><<<(M_DIM / 128) * E_NUM * G * 2, 512, 0, stream>>>(
        h, woT, tfs, eo, eoB, G, M_DIM, H_DIM, 2);

    // 6: combine
    combine_kernel<<<ntok, 256, 0, stream>>>(eo, eoB, slot1, slot2, w1, w2, out, G);
}